// Round 1
// baseline (535.001 us; speedup 1.0000x reference)
//
#include <hip/hip_runtime.h>

#define NV 128
#define NP 8

__device__ __forceinline__ float4 lerp4(float4 a, float4 b, float t) {
    return make_float4(fmaf(t, b.x - a.x, a.x),
                       fmaf(t, b.y - a.y, a.y),
                       fmaf(t, b.z - a.z, a.z),
                       fmaf(t, b.w - a.w, a.w));
}

__global__ __launch_bounds__(256) void voxel_trilerp_kernel(
        const float* __restrict__ ipos,
        const float* __restrict__ grid,
        float* __restrict__ out,
        int nq) {
    const int tid = blockIdx.x * blockDim.x + threadIdx.x;
    const int stride = gridDim.x * blockDim.x;
    const float4* __restrict__ g4 = reinterpret_cast<const float4*>(grid);
    float4* __restrict__ o4 = reinterpret_cast<float4*>(out);

    // float4-unit strides within the grid: one corner = NP floats = 2 float4
    const int Z4 = 2;               // z+1
    const int Y4 = NV * NP / 4;     // 256
    const int X4 = NV * NV * NP / 4; // 32768

    for (int q = tid; q < nq; q += stride) {
        float px = ipos[q * 3 + 0];
        float py = ipos[q * 3 + 1];
        float pz = ipos[q * 3 + 2];

        px = fminf(fmaxf(px, 0.0f), 1.0f) * (float)(NV - 1);
        py = fminf(fmaxf(py, 0.0f), 1.0f) * (float)(NV - 1);
        pz = fminf(fmaxf(pz, 0.0f), 1.0f) * (float)(NV - 1);

        int x0 = min(max((int)floorf(px), 0), NV - 2);
        int y0 = min(max((int)floorf(py), 0), NV - 2);
        int z0 = min(max((int)floorf(pz), 0), NV - 2);

        float fx = px - (float)x0;
        float fy = py - (float)y0;
        float fz = pz - (float)z0;

        int b = x0 * X4 + y0 * Y4 + z0 * Z4;

        // 8 corners, each 2 float4; z0/z1 pairs are contiguous (64 B)
        float4 c00a0 = g4[b];                 // (x0,y0,z0) params 0-3
        float4 c00a1 = g4[b + 1];             // (x0,y0,z0) params 4-7
        float4 c00b0 = g4[b + Z4];            // (x0,y0,z1)
        float4 c00b1 = g4[b + Z4 + 1];
        float4 c01a0 = g4[b + Y4];            // (x0,y1,z0)
        float4 c01a1 = g4[b + Y4 + 1];
        float4 c01b0 = g4[b + Y4 + Z4];
        float4 c01b1 = g4[b + Y4 + Z4 + 1];
        float4 c10a0 = g4[b + X4];            // (x1,y0,z0)
        float4 c10a1 = g4[b + X4 + 1];
        float4 c10b0 = g4[b + X4 + Z4];
        float4 c10b1 = g4[b + X4 + Z4 + 1];
        float4 c11a0 = g4[b + X4 + Y4];       // (x1,y1,z0)
        float4 c11a1 = g4[b + X4 + Y4 + 1];
        float4 c11b0 = g4[b + X4 + Y4 + Z4];
        float4 c11b1 = g4[b + X4 + Y4 + Z4 + 1];

        // lerp along z
        float4 z00_0 = lerp4(c00a0, c00b0, fz);
        float4 z00_1 = lerp4(c00a1, c00b1, fz);
        float4 z01_0 = lerp4(c01a0, c01b0, fz);
        float4 z01_1 = lerp4(c01a1, c01b1, fz);
        float4 z10_0 = lerp4(c10a0, c10b0, fz);
        float4 z10_1 = lerp4(c10a1, c10b1, fz);
        float4 z11_0 = lerp4(c11a0, c11b0, fz);
        float4 z11_1 = lerp4(c11a1, c11b1, fz);

        // lerp along y
        float4 y0_0 = lerp4(z00_0, z01_0, fy);
        float4 y0_1 = lerp4(z00_1, z01_1, fy);
        float4 y1_0 = lerp4(z10_0, z11_0, fy);
        float4 y1_1 = lerp4(z10_1, z11_1, fy);

        // lerp along x
        float4 r0 = lerp4(y0_0, y1_0, fx);
        float4 r1 = lerp4(y0_1, y1_1, fx);

        o4[q * 2 + 0] = r0;
        o4[q * 2 + 1] = r1;
    }
}

extern "C" void kernel_launch(void* const* d_in, const int* in_sizes, int n_in,
                              void* d_out, int out_size, void* d_ws, size_t ws_size,
                              hipStream_t stream) {
    const float* ipos = (const float*)d_in[0];
    const float* grid = (const float*)d_in[1];
    float* out = (float*)d_out;

    const int nq = in_sizes[0] / 3;  // 4194304

    const int block = 256;
    const int grid_blocks = 2048;    // 256 CU x 8 blocks/CU; grid-stride the rest

    voxel_trilerp_kernel<<<grid_blocks, block, 0, stream>>>(ipos, grid, out, nq);
}

// Round 2
// 227.108 us; speedup vs baseline: 2.3557x; 2.3557x over previous
//
#include <hip/hip_runtime.h>
#include <hip/hip_fp16.h>

#define NV 128
#define NP 8
#define TBL_BYTES ((size_t)NV * NV * NV * 64)

// ---------------------------------------------------------------------------
// Repacked table: entry(x,y,z) holds the 4 corners (x+xr, y, z+zr), xr,zr in
// {0,1}, 8 params each, fp16. Entry = 2*2*8*2 = 64 B, 64-aligned.
// In-entry layout (halves): h[xr*16 + zr*8 + p].
// Entry index: ((z*NV + x)*NV + y)  -- y innermost so the two entries a query
// needs (y0, y0+1) are 64 B-adjacent (often one 128 B line).
// ---------------------------------------------------------------------------

__device__ __forceinline__ void cvt8(__half* d, float4 a, float4 b) {
    d[0] = __float2half_rn(a.x); d[1] = __float2half_rn(a.y);
    d[2] = __float2half_rn(a.z); d[3] = __float2half_rn(a.w);
    d[4] = __float2half_rn(b.x); d[5] = __float2half_rn(b.y);
    d[6] = __float2half_rn(b.z); d[7] = __float2half_rn(b.w);
}

__global__ __launch_bounds__(256) void repack_kernel(
        const float* __restrict__ grid, __half* __restrict__ tbl) {
    int t = blockIdx.x * blockDim.x + threadIdx.x;   // ((z*NV + x)*NV + y)
    int y = t & (NV - 1);
    int x = (t >> 7) & (NV - 1);
    int z = t >> 14;
    if (z >= NV) return;

    int x1 = min(x + 1, NV - 1);
    int zo = (z < NV - 1) ? 2 : 0;   // float4-unit offset z -> z+1 (clamped)

    const float4* g4 = reinterpret_cast<const float4*>(grid);
    int b0 = ((x  * NV + y) * NV + z) * 2;
    int b1 = ((x1 * NV + y) * NV + z) * 2;

    float4 c00a = g4[b0],      c00b = g4[b0 + 1];       // (x , z ) params 0-7
    float4 c01a = g4[b0 + zo], c01b = g4[b0 + zo + 1];  // (x , z1)
    float4 c10a = g4[b1],      c10b = g4[b1 + 1];       // (x1, z )
    float4 c11a = g4[b1 + zo], c11b = g4[b1 + zo + 1];  // (x1, z1)

    __half h[32];
    cvt8(h +  0, c00a, c00b);   // xr=0, zr=0
    cvt8(h +  8, c01a, c01b);   // xr=0, zr=1
    cvt8(h + 16, c10a, c10b);   // xr=1, zr=0
    cvt8(h + 24, c11a, c11b);   // xr=1, zr=1

    uint4* dst = reinterpret_cast<uint4*>(tbl) + (size_t)t * 4;
    const uint4* src = reinterpret_cast<const uint4*>(h);
    dst[0] = src[0]; dst[1] = src[1]; dst[2] = src[2]; dst[3] = src[3];
}

__global__ __launch_bounds__(256) void trilerp_tbl_kernel(
        const float* __restrict__ ipos, const __half* __restrict__ tbl,
        float* __restrict__ out, int nq) {
    int q = blockIdx.x * blockDim.x + threadIdx.x;
    if (q >= nq) return;

    float px = ipos[q * 3 + 0];
    float py = ipos[q * 3 + 1];
    float pz = ipos[q * 3 + 2];

    px = fminf(fmaxf(px, 0.0f), 1.0f) * (float)(NV - 1);
    py = fminf(fmaxf(py, 0.0f), 1.0f) * (float)(NV - 1);
    pz = fminf(fmaxf(pz, 0.0f), 1.0f) * (float)(NV - 1);

    int x0 = min((int)px, NV - 2);   // px >= 0, trunc == floor
    int y0 = min((int)py, NV - 2);
    int z0 = min((int)pz, NV - 2);

    float fx = px - (float)x0;
    float fy = py - (float)y0;
    float fz = pz - (float)z0;
    float gx = 1.0f - fx, gy = 1.0f - fy, gz = 1.0f - fz;

    float w00 = gx * gz, w01 = gx * fz, w10 = fx * gz, w11 = fx * fz;

    int e = (z0 * NV + x0) * NV + y0;
    const uint4* t4 = reinterpret_cast<const uint4*>(tbl);

    uint4 E[8];
    E[0] = t4[e * 4 + 0]; E[1] = t4[e * 4 + 1];
    E[2] = t4[e * 4 + 2]; E[3] = t4[e * 4 + 3];
    E[4] = t4[e * 4 + 4]; E[5] = t4[e * 4 + 5];   // entry e+1 (y0+1)
    E[6] = t4[e * 4 + 6]; E[7] = t4[e * 4 + 7];

    const __half2* h2 = reinterpret_cast<const __half2*>(E);
    // entry0: h2[0..15], entry1: h2[16..31]; within entry: xr*8 + zr*4 + p2

    float2 r[4];
    #pragma unroll
    for (int p2 = 0; p2 < 4; ++p2) {
        float2 c00 = __half22float2(h2[ 0 + p2]);   // xr0 zr0
        float2 c01 = __half22float2(h2[ 4 + p2]);   // xr0 zr1
        float2 c10 = __half22float2(h2[ 8 + p2]);   // xr1 zr0
        float2 c11 = __half22float2(h2[12 + p2]);   // xr1 zr1
        float2 d00 = __half22float2(h2[16 + p2]);
        float2 d01 = __half22float2(h2[20 + p2]);
        float2 d10 = __half22float2(h2[24 + p2]);
        float2 d11 = __half22float2(h2[28 + p2]);

        float v0x = w00 * c00.x + w01 * c01.x + w10 * c10.x + w11 * c11.x;
        float v0y = w00 * c00.y + w01 * c01.y + w10 * c10.y + w11 * c11.y;
        float v1x = w00 * d00.x + w01 * d01.x + w10 * d10.x + w11 * d11.x;
        float v1y = w00 * d00.y + w01 * d01.y + w10 * d10.y + w11 * d11.y;

        r[p2].x = gy * v0x + fy * v1x;
        r[p2].y = gy * v0y + fy * v1y;
    }

    float4* o4 = reinterpret_cast<float4*>(out);
    o4[q * 2 + 0] = make_float4(r[0].x, r[0].y, r[1].x, r[1].y);
    o4[q * 2 + 1] = make_float4(r[2].x, r[2].y, r[3].x, r[3].y);
}

// ---------------------------------------------------------------------------
// Fallback (R1 kernel) if workspace can't hold the table.
// ---------------------------------------------------------------------------
__device__ __forceinline__ float4 lerp4(float4 a, float4 b, float t) {
    return make_float4(fmaf(t, b.x - a.x, a.x),
                       fmaf(t, b.y - a.y, a.y),
                       fmaf(t, b.z - a.z, a.z),
                       fmaf(t, b.w - a.w, a.w));
}

__global__ __launch_bounds__(256) void voxel_trilerp_kernel(
        const float* __restrict__ ipos,
        const float* __restrict__ grid,
        float* __restrict__ out,
        int nq) {
    const int tid = blockIdx.x * blockDim.x + threadIdx.x;
    const int stride = gridDim.x * blockDim.x;
    const float4* __restrict__ g4 = reinterpret_cast<const float4*>(grid);
    float4* __restrict__ o4 = reinterpret_cast<float4*>(out);

    const int Z4 = 2;
    const int Y4 = NV * NP / 4;
    const int X4 = NV * NV * NP / 4;

    for (int q = tid; q < nq; q += stride) {
        float px = ipos[q * 3 + 0];
        float py = ipos[q * 3 + 1];
        float pz = ipos[q * 3 + 2];

        px = fminf(fmaxf(px, 0.0f), 1.0f) * (float)(NV - 1);
        py = fminf(fmaxf(py, 0.0f), 1.0f) * (float)(NV - 1);
        pz = fminf(fmaxf(pz, 0.0f), 1.0f) * (float)(NV - 1);

        int x0 = min((int)px, NV - 2);
        int y0 = min((int)py, NV - 2);
        int z0 = min((int)pz, NV - 2);

        float fx = px - (float)x0;
        float fy = py - (float)y0;
        float fz = pz - (float)z0;

        int b = x0 * X4 + y0 * Y4 + z0 * Z4;

        float4 c00a0 = g4[b],              c00a1 = g4[b + 1];
        float4 c00b0 = g4[b + Z4],         c00b1 = g4[b + Z4 + 1];
        float4 c01a0 = g4[b + Y4],         c01a1 = g4[b + Y4 + 1];
        float4 c01b0 = g4[b + Y4 + Z4],    c01b1 = g4[b + Y4 + Z4 + 1];
        float4 c10a0 = g4[b + X4],         c10a1 = g4[b + X4 + 1];
        float4 c10b0 = g4[b + X4 + Z4],    c10b1 = g4[b + X4 + Z4 + 1];
        float4 c11a0 = g4[b + X4 + Y4],    c11a1 = g4[b + X4 + Y4 + 1];
        float4 c11b0 = g4[b + X4 + Y4 + Z4], c11b1 = g4[b + X4 + Y4 + Z4 + 1];

        float4 z00_0 = lerp4(c00a0, c00b0, fz), z00_1 = lerp4(c00a1, c00b1, fz);
        float4 z01_0 = lerp4(c01a0, c01b0, fz), z01_1 = lerp4(c01a1, c01b1, fz);
        float4 z10_0 = lerp4(c10a0, c10b0, fz), z10_1 = lerp4(c10a1, c10b1, fz);
        float4 z11_0 = lerp4(c11a0, c11b0, fz), z11_1 = lerp4(c11a1, c11b1, fz);

        float4 y0_0 = lerp4(z00_0, z01_0, fy), y0_1 = lerp4(z00_1, z01_1, fy);
        float4 y1_0 = lerp4(z10_0, z11_0, fy), y1_1 = lerp4(z10_1, z11_1, fy);

        float4 r0 = lerp4(y0_0, y1_0, fx);
        float4 r1 = lerp4(y0_1, y1_1, fx);

        o4[q * 2 + 0] = r0;
        o4[q * 2 + 1] = r1;
    }
}

extern "C" void kernel_launch(void* const* d_in, const int* in_sizes, int n_in,
                              void* d_out, int out_size, void* d_ws, size_t ws_size,
                              hipStream_t stream) {
    const float* ipos = (const float*)d_in[0];
    const float* grid = (const float*)d_in[1];
    float* out = (float*)d_out;

    const int nq = in_sizes[0] / 3;  // 4194304

    if (ws_size >= TBL_BYTES) {
        __half* tbl = (__half*)d_ws;
        repack_kernel<<<(NV * NV * NV) / 256, 256, 0, stream>>>(grid, tbl);
        trilerp_tbl_kernel<<<(nq + 255) / 256, 256, 0, stream>>>(ipos, tbl, out, nq);
    } else {
        voxel_trilerp_kernel<<<2048, 256, 0, stream>>>(ipos, grid, out, nq);
    }
}